// Round 4
// baseline (148.035 us; speedup 1.0000x reference)
//
#include <hip/hip_runtime.h>

// HistogramLoss: N,C,H,W = 16,3,512,512 ; bins=256
// loss = mean over (48 slices x 256 bins) of ((cnt_s/256 - cnt_t/256)^2), both tensors.

constexpr int SLICES = 48;            // N*C
constexpr int PIX    = 512 * 512;     // H*W per slice
constexpr int BINS   = 256;
constexpr int BPS    = 16;            // blocks per slice-tensor
constexpr int NT     = 256;           // threads per block
constexpr int NWAVE  = NT / 64;
constexpr int F4_PER_BLOCK = PIX / 4 / BPS;   // 4096 float4 per block
constexpr int NBLK   = 2 * SLICES * BPS;      // 1536
constexpr int HWORDS = 2 * SLICES * BINS;     // 24576 == NBLK*16

// monotonic float<->uint mapping so atomicMin on uint gives float min.
// For max we atomicMin the bitwise complement (order-reversed encoding),
// so BOTH arrays initialize with a single 0xFF memset.
__device__ __forceinline__ unsigned enc_f32(float f) {
    unsigned u = __float_as_uint(f);
    return (u & 0x80000000u) ? ~u : (u | 0x80000000u);
}
__device__ __forceinline__ float dec_f32(unsigned u) {
    return __uint_as_float((u & 0x80000000u) ? (u ^ 0x80000000u) : ~u);
}

__global__ __launch_bounds__(NT) void k_minmax(const float* __restrict__ src,
                                               const float* __restrict__ tgt,
                                               unsigned* __restrict__ umin,
                                               unsigned* __restrict__ umaxc,
                                               unsigned* __restrict__ hist) {
    // zero the histogram for the next kernel (safe: k_hist starts after we retire)
    if (threadIdx.x < 16) hist[blockIdx.x * 16 + threadIdx.x] = 0u;

    const int st  = blockIdx.x / BPS;   // 0..95: 0..47 = src slices, 48..95 = tgt slices
    const int sub = blockIdx.x % BPS;
    const float* base = (st < SLICES) ? (src + (size_t)st * PIX)
                                      : (tgt + (size_t)(st - SLICES) * PIX);
    const float4* p = reinterpret_cast<const float4*>(base) + (size_t)sub * F4_PER_BLOCK;

    // two independent accumulator pairs -> shorter dependency chain per iter
    float mn0 = INFINITY, mx0 = -INFINITY, mn1 = INFINITY, mx1 = -INFINITY;
    for (int i = threadIdx.x; i < F4_PER_BLOCK; i += 2 * NT) {
        float4 a = p[i];
        mn0 = fminf(mn0, fminf(fminf(a.x, a.y), fminf(a.z, a.w)));
        mx0 = fmaxf(mx0, fmaxf(fmaxf(a.x, a.y), fmaxf(a.z, a.w)));
        float4 b = p[i + NT];
        mn1 = fminf(mn1, fminf(fminf(b.x, b.y), fminf(b.z, b.w)));
        mx1 = fmaxf(mx1, fmaxf(fmaxf(b.x, b.y), fmaxf(b.z, b.w)));
    }
    float mn = fminf(mn0, mn1), mx = fmaxf(mx0, mx1);
#pragma unroll
    for (int off = 32; off > 0; off >>= 1) {
        mn = fminf(mn, __shfl_xor(mn, off));
        mx = fmaxf(mx, __shfl_xor(mx, off));
    }
    __shared__ float smn[NWAVE], smx[NWAVE];
    const int wave = threadIdx.x >> 6, lane = threadIdx.x & 63;
    if (lane == 0) { smn[wave] = mn; smx[wave] = mx; }
    __syncthreads();
    if (threadIdx.x == 0) {
#pragma unroll
        for (int wv = 1; wv < NWAVE; ++wv) {
            mn = fminf(mn, smn[wv]);
            mx = fmaxf(mx, smx[wv]);
        }
        atomicMin(&umin[st], enc_f32(mn));
        atomicMin(&umaxc[st], ~enc_f32(mx));   // complement -> min encodes max
    }
}

__global__ __launch_bounds__(NT) void k_hist(const float* __restrict__ src,
                                             const float* __restrict__ tgt,
                                             const unsigned* __restrict__ umin,
                                             const unsigned* __restrict__ umaxc,
                                             unsigned* __restrict__ hist) {
    const int st  = blockIdx.x / BPS;
    const int sub = blockIdx.x % BPS;

    __shared__ unsigned lh[NWAVE][BINS];   // per-wave replicas to cut LDS-atomic contention
    for (int i = threadIdx.x; i < NWAVE * BINS; i += NT) (&lh[0][0])[i] = 0u;
    __syncthreads();

    const float mn = dec_f32(umin[st]);
    const float mx = dec_f32(~umaxc[st]);
    float w = mx - mn;
    if (!(w > 0.0f)) w = 1.0f;   // reference safe_width

    const float* base = (st < SLICES) ? (src + (size_t)st * PIX)
                                      : (tgt + (size_t)(st - SLICES) * PIX);
    const float4* p = reinterpret_cast<const float4*>(base) + (size_t)sub * F4_PER_BLOCK;
    unsigned* myh = lh[threadIdx.x >> 6];

    for (int i = threadIdx.x; i < F4_PER_BLOCK; i += NT) {
        float4 v = p[i];
        // exact reference arithmetic: floor((x - mn) / w * 256), clip to [0,255]
        int i0 = (int)floorf((v.x - mn) / w * 256.0f);
        int i1 = (int)floorf((v.y - mn) / w * 256.0f);
        int i2 = (int)floorf((v.z - mn) / w * 256.0f);
        int i3 = (int)floorf((v.w - mn) / w * 256.0f);
        i0 = min(max(i0, 0), BINS - 1);
        i1 = min(max(i1, 0), BINS - 1);
        i2 = min(max(i2, 0), BINS - 1);
        i3 = min(max(i3, 0), BINS - 1);
        atomicAdd(&myh[i0], 1u);
        atomicAdd(&myh[i1], 1u);
        atomicAdd(&myh[i2], 1u);
        atomicAdd(&myh[i3], 1u);
    }
    __syncthreads();

    for (int b = threadIdx.x; b < BINS; b += NT) {
        unsigned s = 0;
#pragma unroll
        for (int wv = 0; wv < NWAVE; ++wv) s += lh[wv][b];
        if (s) atomicAdd(&hist[(size_t)st * BINS + b], s);
    }
}

__global__ __launch_bounds__(NT) void k_loss(const unsigned* __restrict__ hist,
                                             float* __restrict__ out) {
    float acc = 0.0f;
    for (int i = threadIdx.x; i < SLICES * BINS; i += NT) {
        const int s = i >> 8, b = i & 255;
        // counts/256 is exact (pow2 scale); diff of exact multiples of 2^-8 is exact
        const float d = ((float)hist[(size_t)s * BINS + b] -
                         (float)hist[(size_t)(s + SLICES) * BINS + b]) * (1.0f / 256.0f);
        acc += d * d;
    }
#pragma unroll
    for (int off = 32; off > 0; off >>= 1) acc += __shfl_xor(acc, off);
    __shared__ float sacc[NWAVE];
    const int wave = threadIdx.x >> 6, lane = threadIdx.x & 63;
    if (lane == 0) sacc[wave] = acc;
    __syncthreads();
    if (threadIdx.x == 0) {
        float t = 0.0f;
#pragma unroll
        for (int wv = 0; wv < NWAVE; ++wv) t += sacc[wv];
        out[0] = t / (float)(SLICES * BINS);
    }
}

extern "C" void kernel_launch(void* const* d_in, const int* in_sizes, int n_in,
                              void* d_out, int out_size, void* d_ws, size_t ws_size,
                              hipStream_t stream) {
    const float* src = (const float*)d_in[0];
    const float* tgt = (const float*)d_in[1];

    // ws layout: umin[96] | umaxc[96] | hist[96*256]   (all uint32)
    unsigned* umin  = (unsigned*)d_ws;
    unsigned* umaxc = umin + 2 * SLICES;
    unsigned* hist  = umaxc + 2 * SLICES;

    // d_ws is poisoned 0xAA before every timed call — re-init every launch.
    // Single memset: 0xFF is the identity for BOTH min-encoded arrays.
    hipMemsetAsync(umin, 0xFF, 4 * SLICES * sizeof(unsigned), stream);
    // hist is zeroed inside k_minmax (each block zeroes its 16 words).

    k_minmax<<<NBLK, NT, 0, stream>>>(src, tgt, umin, umaxc, hist);
    k_hist  <<<NBLK, NT, 0, stream>>>(src, tgt, umin, umaxc, hist);
    k_loss  <<<1, NT, 0, stream>>>(hist, (float*)d_out);
}

// Round 5
// 136.606 us; speedup vs baseline: 1.0837x; 1.0837x over previous
//
#include <hip/hip_runtime.h>

// HistogramLoss: N,C,H,W = 16,3,512,512 ; bins=256
// loss = mean over (48 slices x 256 bins) of ((cnt_s/256 - cnt_t/256)^2), two tensors.
//
// Structure (validated r4: passed, absmax=0.0, all kernels < 41 us):
//   k_minmax: HBM-bound 100 MB read (~16 us floor @ 6.5 TB/s measured fill BW)
//   k_hist:   L3-resident re-read + LDS-atomic binning (~12-15 us)
//   k_loss:   single-block 12K-word reduce (~2-3 us)
// This round: drop the memset node (per-block plain-store partial min/max,
// no atomics -> no init), widen k_loss to 1024 threads.

constexpr int SLICES = 48;            // N*C
constexpr int PIX    = 512 * 512;     // H*W per slice
constexpr int BINS   = 256;
constexpr int BPS    = 16;            // blocks per slice-tensor
constexpr int NT     = 256;           // threads per block
constexpr int NWAVE  = NT / 64;
constexpr int F4_PER_BLOCK = PIX / 4 / BPS;   // 4096 float4 per block
constexpr int NBLK   = 2 * SLICES * BPS;      // 1536
constexpr int NT_L   = 1024;                  // k_loss block size

__global__ __launch_bounds__(NT) void k_minmax(const float* __restrict__ src,
                                               const float* __restrict__ tgt,
                                               float* __restrict__ pmn,
                                               float* __restrict__ pmx,
                                               unsigned* __restrict__ hist) {
    // zero the histogram for k_hist (safe: k_hist starts after we retire;
    // NBLK*16 == 2*SLICES*BINS exactly)
    if (threadIdx.x < 16) hist[blockIdx.x * 16 + threadIdx.x] = 0u;

    const int st  = blockIdx.x / BPS;   // 0..95: 0..47 = src slices, 48..95 = tgt slices
    const int sub = blockIdx.x % BPS;
    const float* base = (st < SLICES) ? (src + (size_t)st * PIX)
                                      : (tgt + (size_t)(st - SLICES) * PIX);
    const float4* p = reinterpret_cast<const float4*>(base) + (size_t)sub * F4_PER_BLOCK;

    // two independent accumulator pairs -> shorter dependency chain per iter
    float mn0 = INFINITY, mx0 = -INFINITY, mn1 = INFINITY, mx1 = -INFINITY;
    for (int i = threadIdx.x; i < F4_PER_BLOCK; i += 2 * NT) {
        float4 a = p[i];
        mn0 = fminf(mn0, fminf(fminf(a.x, a.y), fminf(a.z, a.w)));
        mx0 = fmaxf(mx0, fmaxf(fmaxf(a.x, a.y), fmaxf(a.z, a.w)));
        float4 b = p[i + NT];
        mn1 = fminf(mn1, fminf(fminf(b.x, b.y), fminf(b.z, b.w)));
        mx1 = fmaxf(mx1, fmaxf(fmaxf(b.x, b.y), fmaxf(b.z, b.w)));
    }
    float mn = fminf(mn0, mn1), mx = fmaxf(mx0, mx1);
#pragma unroll
    for (int off = 32; off > 0; off >>= 1) {
        mn = fminf(mn, __shfl_xor(mn, off));
        mx = fmaxf(mx, __shfl_xor(mx, off));
    }
    __shared__ float smn[NWAVE], smx[NWAVE];
    const int wave = threadIdx.x >> 6, lane = threadIdx.x & 63;
    if (lane == 0) { smn[wave] = mn; smx[wave] = mx; }
    __syncthreads();
    if (threadIdx.x == 0) {
#pragma unroll
        for (int wv = 1; wv < NWAVE; ++wv) {
            mn = fminf(mn, smn[wv]);
            mx = fmaxf(mx, smx[wv]);
        }
        // plain stores, unconditionally written every launch -> no init/memset needed
        pmn[blockIdx.x] = mn;
        pmx[blockIdx.x] = mx;
    }
}

__global__ __launch_bounds__(NT) void k_hist(const float* __restrict__ src,
                                             const float* __restrict__ tgt,
                                             const float* __restrict__ pmn,
                                             const float* __restrict__ pmx,
                                             unsigned* __restrict__ hist) {
    const int st  = blockIdx.x / BPS;
    const int sub = blockIdx.x % BPS;

    __shared__ unsigned lh[NWAVE][BINS];   // per-wave replicas to cut LDS-atomic contention
    for (int i = threadIdx.x; i < NWAVE * BINS; i += NT) (&lh[0][0])[i] = 0u;
    __syncthreads();

    // reduce the 16 per-block partials for this slice (uniform -> scalar loads)
    float mn = pmn[st * BPS], mx = pmx[st * BPS];
#pragma unroll
    for (int k = 1; k < BPS; ++k) {
        mn = fminf(mn, pmn[st * BPS + k]);
        mx = fmaxf(mx, pmx[st * BPS + k]);
    }
    float w = mx - mn;
    if (!(w > 0.0f)) w = 1.0f;   // reference safe_width

    const float* base = (st < SLICES) ? (src + (size_t)st * PIX)
                                      : (tgt + (size_t)(st - SLICES) * PIX);
    const float4* p = reinterpret_cast<const float4*>(base) + (size_t)sub * F4_PER_BLOCK;
    unsigned* myh = lh[threadIdx.x >> 6];

    for (int i = threadIdx.x; i < F4_PER_BLOCK; i += NT) {
        float4 v = p[i];
        // exact reference arithmetic: floor(((x - mn) / w) * 256), clip to [0,255]
        int i0 = (int)floorf((v.x - mn) / w * 256.0f);
        int i1 = (int)floorf((v.y - mn) / w * 256.0f);
        int i2 = (int)floorf((v.z - mn) / w * 256.0f);
        int i3 = (int)floorf((v.w - mn) / w * 256.0f);
        i0 = min(max(i0, 0), BINS - 1);
        i1 = min(max(i1, 0), BINS - 1);
        i2 = min(max(i2, 0), BINS - 1);
        i3 = min(max(i3, 0), BINS - 1);
        atomicAdd(&myh[i0], 1u);
        atomicAdd(&myh[i1], 1u);
        atomicAdd(&myh[i2], 1u);
        atomicAdd(&myh[i3], 1u);
    }
    __syncthreads();

    for (int b = threadIdx.x; b < BINS; b += NT) {
        unsigned s = 0;
#pragma unroll
        for (int wv = 0; wv < NWAVE; ++wv) s += lh[wv][b];
        if (s) atomicAdd(&hist[(size_t)st * BINS + b], s);
    }
}

__global__ __launch_bounds__(NT_L) void k_loss(const unsigned* __restrict__ hist,
                                               float* __restrict__ out) {
    float acc = 0.0f;
    for (int i = threadIdx.x; i < SLICES * BINS; i += NT_L) {
        const int s = i >> 8, b = i & 255;
        // counts/256 is exact (pow2 scale); diff of exact multiples of 2^-8 is exact
        const float d = ((float)hist[(size_t)s * BINS + b] -
                         (float)hist[(size_t)(s + SLICES) * BINS + b]) * (1.0f / 256.0f);
        acc += d * d;
    }
#pragma unroll
    for (int off = 32; off > 0; off >>= 1) acc += __shfl_xor(acc, off);
    __shared__ float sacc[NT_L / 64];
    const int wave = threadIdx.x >> 6, lane = threadIdx.x & 63;
    if (lane == 0) sacc[wave] = acc;
    __syncthreads();
    if (threadIdx.x == 0) {
        float t = 0.0f;
#pragma unroll
        for (int wv = 0; wv < NT_L / 64; ++wv) t += sacc[wv];
        out[0] = t / (float)(SLICES * BINS);
    }
}

extern "C" void kernel_launch(void* const* d_in, const int* in_sizes, int n_in,
                              void* d_out, int out_size, void* d_ws, size_t ws_size,
                              hipStream_t stream) {
    const float* src = (const float*)d_in[0];
    const float* tgt = (const float*)d_in[1];

    // ws layout: pmn[1536] | pmx[1536] | hist[96*256]  (fp32 / fp32 / uint32)
    float*    pmn  = (float*)d_ws;
    float*    pmx  = pmn + NBLK;
    unsigned* hist = (unsigned*)(pmx + NBLK);

    // No memset needed: pmn/pmx are plain-stored by every k_minmax block,
    // hist is zeroed inside k_minmax before k_hist runs (stream order).

    k_minmax<<<NBLK, NT, 0, stream>>>(src, tgt, pmn, pmx, hist);
    k_hist  <<<NBLK, NT, 0, stream>>>(src, tgt, pmn, pmx, hist);
    k_loss  <<<1, NT_L, 0, stream>>>(hist, (float*)d_out);
}